// Round 2
// baseline (458.987 us; speedup 1.0000x reference)
//
#include <hip/hip_runtime.h>

#define IC   32     // in_chunks
#define NE   64     // num_experts
#define D    128    // expert_size
#define IF   4096   // in_features
#define OF   8192   // out_features
#define TB   128    // batch rows per gemm block

// d_ws int layout
#define NNZ_OFF    0               // [64] per-expert nonzero count
#define NACT_OFF   64              // [1]  number of active experts
#define ACT_OFF    65              // [64] active expert ids
#define CHUNK_OFF  129             // [64*32] compacted chunk ids
#define SIGN_OFF   (129 + NE*IC)   // [64*32] compacted signs (as float bits)

// ---- kernel 1: ternarize routing, build compacted per-expert lists ----
__global__ void prep_kernel(const float* __restrict__ routing,
                            const float* __restrict__ noise,
                            int* __restrict__ ws) {
    const int e = threadIdx.x;
    if (e < NE) {
        int cnt = 0;
        for (int i = 0; i < IC; ++i) {
            float w  = routing[i * NE + e];
            float nz = noise[i * NE + e];
            float wn = __fadd_rn(w, __fmul_rn(0.1f, nz));   // exact: mul then add
            float s  = (wn < -0.5f) ? -1.0f : ((wn > 0.5f) ? 1.0f : 0.0f);
            if (s != 0.0f) {
                ws[CHUNK_OFF + e * IC + cnt] = i;
                ((float*)ws)[SIGN_OFF + e * IC + cnt] = s;
                ++cnt;
            }
        }
        ws[NNZ_OFF + e] = cnt;
    }
    __syncthreads();
    if (e == 0) {
        int na = 0;
        for (int k = 0; k < NE; ++k)
            if (ws[NNZ_OFF + k] > 0) ws[ACT_OFF + na++] = k;
        ws[NACT_OFF] = na;
    }
}

// ---- kernel 2: zero-fill inactive expert columns (pure streaming) ----
__global__ __launch_bounds__(256)
void fill_kernel(const int* __restrict__ ws, float4* __restrict__ out4, int B) {
    __shared__ int s_act[NE];
    if (threadIdx.x < NE) s_act[threadIdx.x] = ws[NNZ_OFF + threadIdx.x];
    __syncthreads();
    const float4 z = make_float4(0.f, 0.f, 0.f, 0.f);
    const size_t total = (size_t)B * (OF / 4);
    const size_t stride = (size_t)gridDim.x * blockDim.x;
    for (size_t idx = (size_t)blockIdx.x * blockDim.x + threadIdx.x;
         idx < total; idx += stride) {
        int col4 = (int)(idx & (OF / 4 - 1));   // 0..2047
        int e    = col4 >> 5;                   // 32 float4 per expert column
        if (s_act[e] == 0) out4[idx] = z;
    }
}

// ---- kernel 3: GEMM for active experts only ----
__global__ __launch_bounds__(256, 1)
void gemm_kernel(const float* __restrict__ x,
                 const float* __restrict__ We,
                 const int* __restrict__ ws,
                 float* __restrict__ out) {
    __shared__ float sWe[D * D];   // 64 KB, transposed+swizzled
    __shared__ float sXr[TB * D];  // 64 KB, transposed+swizzled
    __shared__ int   s_chunk[IC];
    __shared__ float s_csign[IC];

    const int nact = ws[NACT_OFF];
    if ((int)blockIdx.y >= nact) return;       // inactive slot: exit fast
    const int e   = ws[ACT_OFF + blockIdx.y];
    const int nnz = ws[NNZ_OFF + e];
    const int t   = threadIdx.x;
    const int bt  = blockIdx.x;

    if (t < nnz) {
        s_chunk[t] = ws[CHUNK_OFF + e * IC + t];
        s_csign[t] = ((const float*)ws)[SIGN_OFF + e * IC + t];
    }
    __syncthreads();

    const int c4 = t & 31;   // float4 lane within a 128-float row
    const int r0 = t >> 5;   // 0..7

    // stage We[e] transposed: (r,j) -> sWe[j*128 + ((r>>3)^((j>>2)&15))*8 + (r&7)]
    const float4* We4 = (const float4*)(We + (size_t)e * D * D);
    #pragma unroll
    for (int p = 0; p < D / 8; ++p) {
        int r = p * 8 + r0;
        float4 w4 = We4[r * (D / 4) + c4];
        float wv[4] = {w4.x, w4.y, w4.z, w4.w};
        #pragma unroll
        for (int k = 0; k < 4; ++k) {
            int j = c4 * 4 + k;
            int blk = (r >> 3) ^ ((j >> 2) & 15);
            sWe[j * D + blk * 8 + (r & 7)] = wv[k];
        }
    }

    // compute x_routed tile, stage transposed+swizzled (chunk order ascending -> exact)
    const float4* x4p = (const float4*)x;
    const size_t xrow4 = IF / 4;
    #pragma unroll
    for (int p = 0; p < TB / 8; ++p) {
        int b = p * 8 + r0;
        size_t row = (size_t)(bt * TB + b);
        float4 acc = make_float4(0.f, 0.f, 0.f, 0.f);
        for (int m = 0; m < nnz; ++m) {
            int   i = s_chunk[m];
            float s = s_csign[m];
            float4 v = x4p[row * xrow4 + i * (D / 4) + c4];
            acc.x += s * v.x; acc.y += s * v.y;
            acc.z += s * v.z; acc.w += s * v.w;
        }
        float av[4] = {acc.x, acc.y, acc.z, acc.w};
        #pragma unroll
        for (int k = 0; k < 4; ++k) {
            int j = c4 * 4 + k;
            int blk = (b >> 3) ^ ((j >> 2) & 15);
            sXr[j * TB + blk * 8 + (b & 7)] = av[k];
        }
    }
    __syncthreads();

    // register-tiled fp32 GEMM: out[b][r] = sum_j WeT[j][r] * XrT[j][b]
    const int rg = t & 15;
    const int bg = t >> 4;
    float acc[8][8];
    #pragma unroll
    for (int a = 0; a < 8; ++a)
        #pragma unroll
        for (int c = 0; c < 8; ++c) acc[a][c] = 0.f;

    #pragma unroll 2
    for (int j = 0; j < D; ++j) {
        const int sw = (j >> 2) & 15;
        const float4* wr = (const float4*)&sWe[j * D  + ((rg ^ sw) << 3)];
        const float4* xr = (const float4*)&sXr[j * TB + ((bg ^ sw) << 3)];
        float4 w0 = wr[0], w1 = wr[1];
        float4 x0 = xr[0], x1 = xr[1];
        float wv[8] = {w0.x, w0.y, w0.z, w0.w, w1.x, w1.y, w1.z, w1.w};
        float xv[8] = {x0.x, x0.y, x0.z, x0.w, x1.x, x1.y, x1.z, x1.w};
        #pragma unroll
        for (int a = 0; a < 8; ++a)
            #pragma unroll
            for (int c = 0; c < 8; ++c)
                acc[a][c] += wv[a] * xv[c];
    }

    // epilogue: rows bt*TB + bg*8 + c, cols e*128 + rg*8 + {0..7}
    float4* out4 = (float4*)out;
    const size_t orow4 = OF / 4;
    #pragma unroll
    for (int c = 0; c < 8; ++c) {
        size_t row  = (size_t)(bt * TB + bg * 8 + c);
        size_t base = row * orow4 + e * (D / 4) + rg * 2;
        out4[base]     = make_float4(acc[0][c], acc[1][c], acc[2][c], acc[3][c]);
        out4[base + 1] = make_float4(acc[4][c], acc[5][c], acc[6][c], acc[7][c]);
    }
}

extern "C" void kernel_launch(void* const* d_in, const int* in_sizes, int n_in,
                              void* d_out, int out_size, void* d_ws, size_t ws_size,
                              hipStream_t stream) {
    const float* x       = (const float*)d_in[0];
    const float* routing = (const float*)d_in[1];
    const float* We      = (const float*)d_in[2];
    const float* noise   = (const float*)d_in[3];
    float* out = (float*)d_out;
    int*   ws  = (int*)d_ws;

    const int B = in_sizes[0] / IF;   // 8192

    prep_kernel<<<1, 64, 0, stream>>>(routing, noise, ws);
    fill_kernel<<<2048, 256, 0, stream>>>(ws, (float4*)out, B);
    dim3 grid(B / TB, NE);
    gemm_kernel<<<grid, 256, 0, stream>>>(x, We, ws, out);
}

// Round 4
// 431.058 us; speedup vs baseline: 1.0648x; 1.0648x over previous
//
#include <hip/hip_runtime.h>

#define IC   32     // in_chunks
#define NE   64     // num_experts
#define D    128    // expert_size
#define IF   4096   // in_features
#define OF   8192   // out_features
#define TB   128    // batch rows per block

typedef float vf4 __attribute__((ext_vector_type(4)));   // native vec for NT stores

// d_ws int layout
#define NNZ_OFF    0                 // [64]  per-expert nonzero count
#define NACT_OFF   64                // [1]   number of active experts
#define ACT_OFF    65                // [64]  active expert ids
#define INACT_OFF  129               // [64]  inactive expert ids
#define CHUNK_OFF  193               // [64*32] compacted chunk ids
#define SIGN_OFF   (193 + NE * IC)   // [64*32] compacted signs (float bits)

// ---- kernel 1: ternarize + compact, fully parallel, 1 wave ----
__global__ void prep_kernel(const float* __restrict__ routing,
                            const float* __restrict__ noise,
                            int* __restrict__ ws) {
    __shared__ float s_sign[IC][NE];   // 8 KB
    const int t = threadIdx.x;         // 0..63 (one wave)

    #pragma unroll
    for (int i = 0; i < IC; ++i) {     // coalesced: 64 consecutive floats per i
        float w  = routing[i * NE + t];
        float nz = noise[i * NE + t];
        float wn = __fadd_rn(w, __fmul_rn(0.1f, nz));   // exact: mul then add
        s_sign[i][t] = (wn < -0.5f) ? -1.0f : ((wn > 0.5f) ? 1.0f : 0.0f);
    }
    __syncthreads();

    // thread t owns expert t: compact its chunk list (ascending i -> exact sum order)
    int cnt = 0;
    #pragma unroll
    for (int i = 0; i < IC; ++i) {
        float sgn = s_sign[i][t];
        if (sgn != 0.0f) {
            ws[CHUNK_OFF + t * IC + cnt] = i;
            ((float*)ws)[SIGN_OFF + t * IC + cnt] = sgn;
            ++cnt;
        }
    }
    ws[NNZ_OFF + t] = cnt;

    // active/inactive lists via ballot prefix
    unsigned long long mask = __ballot(cnt > 0);
    unsigned long long below = mask & ((t == 0) ? 0ull : (~0ull >> (64 - t)));
    int act_before = (int)__popcll(below);
    if (cnt > 0) ws[ACT_OFF + act_before] = t;
    else         ws[INACT_OFF + (t - act_before)] = t;
    if (t == 0)  ws[NACT_OFF] = (int)__popcll(mask);
}

// ---- kernel 2: slot-dispatched gemm-or-fill; every output byte written once ----
__global__ __launch_bounds__(256, 1)
void main_kernel(const float* __restrict__ x,
                 const float* __restrict__ We,
                 const int* __restrict__ ws,
                 float* __restrict__ out) {
    __shared__ float sWe[D * D];   // 64 KB, transposed+swizzled
    __shared__ float sXr[TB * D];  // 64 KB, transposed+swizzled
    __shared__ int   s_chunk[IC];
    __shared__ float s_csign[IC];

    const int t  = threadIdx.x;
    const int bt = blockIdx.x;
    const int s  = blockIdx.y;
    const int nact = ws[NACT_OFF];

    const int c4 = t & 31;   // float4 lane within a 128-float row
    const int r0 = t >> 5;   // 0..7
    float4* out4 = (float4*)out;
    const size_t orow4 = OF / 4;

    if (s >= nact) {
        // fill duty: zero one inactive expert column for this 128-row tile
        const int e = ws[INACT_OFF + (s - nact)];
        vf4* outv = (vf4*)out;
        const vf4 z = (vf4){0.f, 0.f, 0.f, 0.f};
        #pragma unroll
        for (int p = 0; p < TB / 8; ++p) {
            size_t row = (size_t)(bt * TB + p * 8 + r0);
            __builtin_nontemporal_store(z, &outv[row * orow4 + e * (D / 4) + c4]);
        }
        return;
    }

    const int e   = ws[ACT_OFF + s];
    const int nnz = ws[NNZ_OFF + e];
    if (t < nnz) {
        s_chunk[t] = ws[CHUNK_OFF + e * IC + t];
        s_csign[t] = ((const float*)ws)[SIGN_OFF + e * IC + t];
    }
    __syncthreads();

    // stage We[e] transposed: (r,j) -> sWe[j*128 + ((r>>3)^((j>>2)&15))*8 + (r&7)]
    const float4* We4 = (const float4*)(We + (size_t)e * D * D);
    #pragma unroll
    for (int p = 0; p < D / 8; ++p) {
        int r = p * 8 + r0;
        float4 w4 = We4[r * (D / 4) + c4];
        float wv[4] = {w4.x, w4.y, w4.z, w4.w};
        #pragma unroll
        for (int k = 0; k < 4; ++k) {
            int j = c4 * 4 + k;
            int blk = (r >> 3) ^ ((j >> 2) & 15);
            sWe[j * D + blk * 8 + (r & 7)] = wv[k];
        }
    }

    // x_routed tile, staged transposed+swizzled (ascending chunk order -> exact)
    const float4* x4p = (const float4*)x;
    const size_t xrow4 = IF / 4;
    #pragma unroll
    for (int p = 0; p < TB / 8; ++p) {
        int b = p * 8 + r0;
        size_t row = (size_t)(bt * TB + b);
        float4 acc = make_float4(0.f, 0.f, 0.f, 0.f);
        for (int m = 0; m < nnz; ++m) {
            int   i  = s_chunk[m];
            float sg = s_csign[m];
            float4 v = x4p[row * xrow4 + i * (D / 4) + c4];
            acc.x += sg * v.x; acc.y += sg * v.y;
            acc.z += sg * v.z; acc.w += sg * v.w;
        }
        float av[4] = {acc.x, acc.y, acc.z, acc.w};
        #pragma unroll
        for (int k = 0; k < 4; ++k) {
            int j = c4 * 4 + k;
            int blk = (b >> 3) ^ ((j >> 2) & 15);
            sXr[j * TB + blk * 8 + (b & 7)] = av[k];
        }
    }
    __syncthreads();

    // register-tiled fp32 GEMM: out[b][r] = sum_j WeT[j][r] * XrT[j][b]
    const int rg = t & 15;
    const int bg = t >> 4;
    float acc[8][8];
    #pragma unroll
    for (int a = 0; a < 8; ++a)
        #pragma unroll
        for (int c = 0; c < 8; ++c) acc[a][c] = 0.f;

    #pragma unroll 2
    for (int j = 0; j < D; ++j) {
        const int sw = (j >> 2) & 15;
        const float4* wr = (const float4*)&sWe[j * D  + ((rg ^ sw) << 3)];
        const float4* xr = (const float4*)&sXr[j * TB + ((bg ^ sw) << 3)];
        float4 w0 = wr[0], w1 = wr[1];
        float4 x0 = xr[0], x1 = xr[1];
        float wv[8] = {w0.x, w0.y, w0.z, w0.w, w1.x, w1.y, w1.z, w1.w};
        float xv[8] = {x0.x, x0.y, x0.z, x0.w, x1.x, x1.y, x1.z, x1.w};
        #pragma unroll
        for (int a = 0; a < 8; ++a)
            #pragma unroll
            for (int c = 0; c < 8; ++c)
                acc[a][c] += wv[a] * xv[c];
    }

    // epilogue: rows bt*TB + bg*8 + c, cols e*128 + rg*8 + {0..7}
    #pragma unroll
    for (int c = 0; c < 8; ++c) {
        size_t row  = (size_t)(bt * TB + bg * 8 + c);
        size_t base = row * orow4 + e * (D / 4) + rg * 2;
        out4[base]     = make_float4(acc[0][c], acc[1][c], acc[2][c], acc[3][c]);
        out4[base + 1] = make_float4(acc[4][c], acc[5][c], acc[6][c], acc[7][c]);
    }
}

extern "C" void kernel_launch(void* const* d_in, const int* in_sizes, int n_in,
                              void* d_out, int out_size, void* d_ws, size_t ws_size,
                              hipStream_t stream) {
    const float* x       = (const float*)d_in[0];
    const float* routing = (const float*)d_in[1];
    const float* We      = (const float*)d_in[2];
    const float* noise   = (const float*)d_in[3];
    float* out = (float*)d_out;
    int*   ws  = (int*)d_ws;

    const int B = in_sizes[0] / IF;   // 8192

    prep_kernel<<<1, 64, 0, stream>>>(routing, noise, ws);
    dim3 grid(B / TB, NE);            // (64, 64)
    main_kernel<<<grid, 256, 0, stream>>>(x, We, ws, out);
}

// Round 6
// 400.138 us; speedup vs baseline: 1.1471x; 1.0773x over previous
//
#include <hip/hip_runtime.h>

#define IC   32     // in_chunks
#define NE   64     // num_experts
#define D    128    // expert_size
#define IF   4096   // in_features
#define OF   8192   // out_features
#define TB   128    // batch rows per block
#define KH   64     // K half-length (j-dimension split)

typedef float vf4 __attribute__((ext_vector_type(4)));   // native vec for NT stores

// d_ws int layout
#define NNZ_OFF    0                 // [64]  per-expert nonzero count
#define NACT_OFF   64                // [1]   number of active experts
#define ACT_OFF    65                // [64]  active expert ids
#define INACT_OFF  129               // [64]  inactive expert ids
#define CHUNK_OFF  193               // [64*32] compacted chunk ids
#define SIGN_OFF   (193 + NE * IC)   // [64*32] compacted signs (float bits)

// ---- kernel 1: ternarize + compact, fully parallel, 1 wave ----
__global__ void prep_kernel(const float* __restrict__ routing,
                            const float* __restrict__ noise,
                            int* __restrict__ ws) {
    __shared__ float s_sign[IC][NE];   // 8 KB
    const int t = threadIdx.x;         // 0..63 (one wave)

    #pragma unroll
    for (int i = 0; i < IC; ++i) {     // coalesced: 64 consecutive floats per i
        float w  = routing[i * NE + t];
        float nz = noise[i * NE + t];
        float wn = __fadd_rn(w, __fmul_rn(0.1f, nz));   // exact: mul then add
        s_sign[i][t] = (wn < -0.5f) ? -1.0f : ((wn > 0.5f) ? 1.0f : 0.0f);
    }
    __syncthreads();

    // thread t owns expert t: compact its chunk list (ascending i -> exact sum order)
    int cnt = 0;
    #pragma unroll
    for (int i = 0; i < IC; ++i) {
        float sgn = s_sign[i][t];
        if (sgn != 0.0f) {
            ws[CHUNK_OFF + t * IC + cnt] = i;
            ((float*)ws)[SIGN_OFF + t * IC + cnt] = sgn;
            ++cnt;
        }
    }
    ws[NNZ_OFF + t] = cnt;

    unsigned long long mask = __ballot(cnt > 0);
    unsigned long long below = mask & ((t == 0) ? 0ull : (~0ull >> (64 - t)));
    int act_before = (int)__popcll(below);
    if (cnt > 0) ws[ACT_OFF + act_before] = t;
    else         ws[INACT_OFF + (t - act_before)] = t;
    if (t == 0)  ws[NACT_OFF] = (int)__popcll(mask);
}

// ---- kernel 2: gemm-or-fill, K split in halves -> 64KB LDS -> 2 blocks/CU ----
__global__ __launch_bounds__(256, 2)
void main_kernel(const float* __restrict__ x,
                 const float* __restrict__ We,
                 const int* __restrict__ ws,
                 float* __restrict__ out) {
    __shared__ float sWe[KH * D];    // 32 KB, half-K of We[e], j-major, swizzled
    __shared__ float sXr[KH * TB];   // 32 KB, half-K of x_routed tile, j-major, swizzled
    __shared__ int   s_chunk[IC];
    __shared__ float s_csign[IC];

    const int t  = threadIdx.x;
    const int bt = blockIdx.x;
    const int s  = blockIdx.y;
    const int nact = ws[NACT_OFF];

    float4* out4 = (float4*)out;
    const size_t orow4 = OF / 4;

    if (s >= nact) {
        // fill duty: zero one inactive expert column for this 128-row tile
        const int e = ws[INACT_OFF + (s - nact)];
        const int c4 = t & 31;
        const int r0 = t >> 5;
        vf4* outv = (vf4*)out;
        const vf4 z = (vf4){0.f, 0.f, 0.f, 0.f};
        #pragma unroll
        for (int p = 0; p < TB / 8; ++p) {
            size_t row = (size_t)(bt * TB + p * 8 + r0);
            __builtin_nontemporal_store(z, &outv[row * orow4 + e * (D / 4) + c4]);
        }
        return;
    }

    const int e   = ws[ACT_OFF + s];
    const int nnz = ws[NNZ_OFF + e];
    if (t < nnz) {
        s_chunk[t] = ws[CHUNK_OFF + e * IC + t];
        s_csign[t] = ((const float*)ws)[SIGN_OFF + e * IC + t];
    }
    __syncthreads();

    const int c4h = t & 15;   // float4 lane within a 64-float half-row
    const int r0h = t >> 4;   // 0..15
    const int rg  = t & 15;   // r-block for gemm
    const int bg  = t >> 4;   // b-block for gemm

    const float4* We4 = (const float4*)(We + (size_t)e * D * D);
    const float4* x4p = (const float4*)x;

    float acc[8][8];
    #pragma unroll
    for (int a = 0; a < 8; ++a)
        #pragma unroll
        for (int c = 0; c < 8; ++c) acc[a][c] = 0.f;

    #pragma unroll
    for (int h = 0; h < 2; ++h) {
        if (h) __syncthreads();   // all waves done reading previous half

        // stage We[e][:, h*64 : h*64+64] transposed+swizzled:
        // (r, jl) -> sWe[jl*128 + ((r>>3)^((jl>>2)&15))*8 + (r&7)]
        #pragma unroll
        for (int p = 0; p < 8; ++p) {
            int r = p * 16 + r0h;
            float4 w4 = We4[r * (D / 4) + h * (KH / 4) + c4h];
            float wv[4] = {w4.x, w4.y, w4.z, w4.w};
            #pragma unroll
            for (int k = 0; k < 4; ++k) {
                int jl  = c4h * 4 + k;
                int blk = (r >> 3) ^ ((jl >> 2) & 15);
                sWe[jl * D + blk * 8 + (r & 7)] = wv[k];
            }
        }

        // x_routed half-tile (ascending chunk order -> exact), transposed+swizzled
        #pragma unroll
        for (int p = 0; p < 8; ++p) {
            int b = p * 16 + r0h;
            size_t row = (size_t)(bt * TB + b);
            float4 acc4 = make_float4(0.f, 0.f, 0.f, 0.f);
            for (int m = 0; m < nnz; ++m) {
                int   i  = s_chunk[m];
                float sg = s_csign[m];
                float4 v = x4p[row * (IF / 4) + i * (D / 4) + h * (KH / 4) + c4h];
                acc4.x += sg * v.x; acc4.y += sg * v.y;
                acc4.z += sg * v.z; acc4.w += sg * v.w;
            }
            float av[4] = {acc4.x, acc4.y, acc4.z, acc4.w};
            #pragma unroll
            for (int k = 0; k < 4; ++k) {
                int jl  = c4h * 4 + k;
                int blk = (b >> 3) ^ ((jl >> 2) & 15);
                sXr[jl * TB + blk * 8 + (b & 7)] = av[k];
            }
        }
        __syncthreads();

        // register-tiled fp32 GEMM over this K-half (j ascending -> exact order)
        #pragma unroll 2
        for (int jl = 0; jl < KH; ++jl) {
            const int sw = (jl >> 2) & 15;
            const float4* wr = (const float4*)&sWe[jl * D  + ((rg ^ sw) << 3)];
            const float4* xr = (const float4*)&sXr[jl * TB + ((bg ^ sw) << 3)];
            float4 w0 = wr[0], w1 = wr[1];
            float4 x0 = xr[0], x1 = xr[1];
            float wv[8] = {w0.x, w0.y, w0.z, w0.w, w1.x, w1.y, w1.z, w1.w};
            float xv[8] = {x0.x, x0.y, x0.z, x0.w, x1.x, x1.y, x1.z, x1.w};
            #pragma unroll
            for (int a = 0; a < 8; ++a)
                #pragma unroll
                for (int c = 0; c < 8; ++c)
                    acc[a][c] += wv[a] * xv[c];
        }
    }

    // epilogue: rows bt*TB + bg*8 + c, cols e*128 + rg*8 + {0..7}
    #pragma unroll
    for (int c = 0; c < 8; ++c) {
        size_t row  = (size_t)(bt * TB + bg * 8 + c);
        size_t base = row * orow4 + e * (D / 4) + rg * 2;
        out4[base]     = make_float4(acc[0][c], acc[1][c], acc[2][c], acc[3][c]);
        out4[base + 1] = make_float4(acc[4][c], acc[5][c], acc[6][c], acc[7][c]);
    }
}

extern "C" void kernel_launch(void* const* d_in, const int* in_sizes, int n_in,
                              void* d_out, int out_size, void* d_ws, size_t ws_size,
                              hipStream_t stream) {
    const float* x       = (const float*)d_in[0];
    const float* routing = (const float*)d_in[1];
    const float* We      = (const float*)d_in[2];
    const float* noise   = (const float*)d_in[3];
    float* out = (float*)d_out;
    int*   ws  = (int*)d_ws;

    const int B = in_sizes[0] / IF;   // 8192

    prep_kernel<<<1, 64, 0, stream>>>(routing, noise, ws);
    dim3 grid(B / TB, NE);            // (64, 64)
    main_kernel<<<grid, 256, 0, stream>>>(x, We, ws, out);
}

// Round 7
// 391.637 us; speedup vs baseline: 1.1720x; 1.0217x over previous
//
#include <hip/hip_runtime.h>

#define IC   32     // in_chunks
#define NE   64     // num_experts
#define D    128    // expert_size
#define IF   4096   // in_features
#define OF   8192   // out_features
#define TB   128    // batch rows per block
#define KH   64     // K half-length (j-dimension split)

typedef float vf4 __attribute__((ext_vector_type(4)));   // native vec for NT stores

// single fused kernel: grid (B/TB, NE); each block ternarizes its own expert
// column (cheap, L2-resident) then does GEMM (active) or NT zero-fill (inactive)
__global__ __launch_bounds__(256, 2)
void moe_kernel(const float* __restrict__ x,
                const float* __restrict__ routing,
                const float* __restrict__ We,
                const float* __restrict__ noise,
                float* __restrict__ out) {
    __shared__ float sWe[KH * D];    // 32 KB, half-K of We[e], j-major, swizzled
    __shared__ float sXr[KH * TB];   // 32 KB, half-K of x_routed tile, j-major, swizzled
    __shared__ int   s_chunk[IC];
    __shared__ float s_csign[IC];
    __shared__ int   s_nnz;

    const int t  = threadIdx.x;
    const int bt = blockIdx.x;
    const int e  = blockIdx.y;

    // ---- wave 0: ternarize this expert's routing column, compact via ballot ----
    if (t < 64) {
        float sgn = 0.0f;
        if (t < IC) {
            float w  = routing[t * NE + e];
            float nz = noise[t * NE + e];
            float wn = __fadd_rn(w, __fmul_rn(0.1f, nz));   // exact: mul then add
            sgn = (wn < -0.5f) ? -1.0f : ((wn > 0.5f) ? 1.0f : 0.0f);
        }
        unsigned long long mask  = __ballot(sgn != 0.0f);
        unsigned long long below = mask & ((t == 0) ? 0ull : (~0ull >> (64 - t)));
        int pos = (int)__popcll(below);
        if (sgn != 0.0f) {               // ascending chunk order preserved
            s_chunk[pos] = t;
            s_csign[pos] = sgn;
        }
        if (t == 0) s_nnz = (int)__popcll(mask);
    }
    __syncthreads();
    const int nnz = s_nnz;

    float4* out4 = (float4*)out;
    const size_t orow4 = OF / 4;

    if (nnz == 0) {
        // fill duty: zero this (bt, e) output tile with nontemporal stores
        const int c4 = t & 31;
        const int r0 = t >> 5;
        vf4* outv = (vf4*)out;
        const vf4 z = (vf4){0.f, 0.f, 0.f, 0.f};
        #pragma unroll
        for (int p = 0; p < TB / 8; ++p) {
            size_t row = (size_t)(bt * TB + p * 8 + r0);
            __builtin_nontemporal_store(z, &outv[row * orow4 + e * (D / 4) + c4]);
        }
        return;
    }

    const int c4h = t & 15;   // float4 lane within a 64-float half-row
    const int r0h = t >> 4;   // 0..15
    const int rg  = t & 15;   // r-block for gemm
    const int bg  = t >> 4;   // b-block for gemm

    const float4* We4 = (const float4*)(We + (size_t)e * D * D);
    const float4* x4p = (const float4*)x;

    float acc[8][8];
    #pragma unroll
    for (int a = 0; a < 8; ++a)
        #pragma unroll
        for (int c = 0; c < 8; ++c) acc[a][c] = 0.f;

    #pragma unroll
    for (int h = 0; h < 2; ++h) {
        if (h) __syncthreads();   // all waves done reading previous half

        // stage We[e][:, h*64 : h*64+64] transposed+swizzled:
        // (r, jl) -> sWe[jl*128 + ((r>>3)^((jl>>2)&15))*8 + (r&7)]
        #pragma unroll
        for (int p = 0; p < 8; ++p) {
            int r = p * 16 + r0h;
            float4 w4 = We4[r * (D / 4) + h * (KH / 4) + c4h];
            float wv[4] = {w4.x, w4.y, w4.z, w4.w};
            #pragma unroll
            for (int k = 0; k < 4; ++k) {
                int jl  = c4h * 4 + k;
                int blk = (r >> 3) ^ ((jl >> 2) & 15);
                sWe[jl * D + blk * 8 + (r & 7)] = wv[k];
            }
        }

        // x_routed half-tile (ascending chunk order -> exact), transposed+swizzled
        #pragma unroll
        for (int p = 0; p < 8; ++p) {
            int b = p * 16 + r0h;
            size_t row = (size_t)(bt * TB + b);
            float4 acc4 = make_float4(0.f, 0.f, 0.f, 0.f);
            for (int m = 0; m < nnz; ++m) {
                int   i  = s_chunk[m];
                float sg = s_csign[m];
                float4 v = x4p[row * (IF / 4) + i * (D / 4) + h * (KH / 4) + c4h];
                acc4.x += sg * v.x; acc4.y += sg * v.y;
                acc4.z += sg * v.z; acc4.w += sg * v.w;
            }
            float av[4] = {acc4.x, acc4.y, acc4.z, acc4.w};
            #pragma unroll
            for (int k = 0; k < 4; ++k) {
                int jl  = c4h * 4 + k;
                int blk = (b >> 3) ^ ((jl >> 2) & 15);
                sXr[jl * TB + blk * 8 + (b & 7)] = av[k];
            }
        }
        __syncthreads();

        // register-tiled fp32 GEMM over this K-half (j ascending -> exact order)
        #pragma unroll 2
        for (int jl = 0; jl < KH; ++jl) {
            const int sw = (jl >> 2) & 15;
            const float4* wr = (const float4*)&sWe[jl * D  + ((rg ^ sw) << 3)];
            const float4* xr = (const float4*)&sXr[jl * TB + ((bg ^ sw) << 3)];
            float4 w0 = wr[0], w1 = wr[1];
            float4 x0 = xr[0], x1 = xr[1];
            float wv[8] = {w0.x, w0.y, w0.z, w0.w, w1.x, w1.y, w1.z, w1.w};
            float xv[8] = {x0.x, x0.y, x0.z, x0.w, x1.x, x1.y, x1.z, x1.w};
            #pragma unroll
            for (int a = 0; a < 8; ++a)
                #pragma unroll
                for (int c = 0; c < 8; ++c)
                    acc[a][c] += wv[a] * xv[c];
        }
    }

    // epilogue: rows bt*TB + bg*8 + c, cols e*128 + rg*8 + {0..7}
    #pragma unroll
    for (int c = 0; c < 8; ++c) {
        size_t row  = (size_t)(bt * TB + bg * 8 + c);
        size_t base = row * orow4 + e * (D / 4) + rg * 2;
        out4[base]     = make_float4(acc[0][c], acc[1][c], acc[2][c], acc[3][c]);
        out4[base + 1] = make_float4(acc[4][c], acc[5][c], acc[6][c], acc[7][c]);
    }
}

extern "C" void kernel_launch(void* const* d_in, const int* in_sizes, int n_in,
                              void* d_out, int out_size, void* d_ws, size_t ws_size,
                              hipStream_t stream) {
    const float* x       = (const float*)d_in[0];
    const float* routing = (const float*)d_in[1];
    const float* We      = (const float*)d_in[2];
    const float* noise   = (const float*)d_in[3];
    float* out = (float*)d_out;

    const int B = in_sizes[0] / IF;   // 8192
    dim3 grid(B / TB, NE);            // (64, 64)
    moe_kernel<<<grid, 256, 0, stream>>>(x, routing, We, noise, out);
}